// Round 7
// baseline (1312.544 us; speedup 1.0000x reference)
//
#include <hip/hip_runtime.h>
#include <hip/hip_bf16.h>
#include <stdint.h>

typedef __bf16 bf16x8 __attribute__((ext_vector_type(8)));
typedef float  f32x4  __attribute__((ext_vector_type(4)));

#define M_ROWS 8192
#define K_DIM  2048
#define HIDN   1024
#define BM 256
#define BN 256
#define BK 32
#define NTILES (K_DIM / BK)   /* 64 */
#define NITER  (NTILES / 2)   /* 32 */

__device__ __forceinline__ unsigned short f2bf(float f) {
    __hip_bfloat16 h = __float2bfloat16(f);
    return *reinterpret_cast<unsigned short*>(&h);
}

// ---------------- fused pack kernel (verified) ----------------
__global__ __launch_bounds__(256) void pack_kernel(const float* __restrict__ x,
                                                   const float* __restrict__ h0,
                                                   const float* __restrict__ Wx,
                                                   const float* __restrict__ Wh,
                                                   unsigned short* __restrict__ A,
                                                   unsigned short* __restrict__ Bp) {
    if (blockIdx.x < 16384) {
        int idx = blockIdx.x * 256 + threadIdx.x;
        int row = idx >> 9;
        int col = (idx & 511) << 2;
        const float* src = (col < HIDN) ? (x + (int64_t)row * HIDN + col)
                                        : (h0 + (int64_t)row * HIDN + (col - HIDN));
        float4 v = *reinterpret_cast<const float4*>(src);
        ushort4 o;
        o.x = f2bf(v.x); o.y = f2bf(v.y); o.z = f2bf(v.z); o.w = f2bf(v.w);
        *reinterpret_cast<ushort4*>(A + (int64_t)idx * 4) = o;
    } else {
        int idx = (blockIdx.x - 16384) * 256 + threadIdx.x;
        int j   = idx >> 9;
        int col = (idx & 511) << 2;
        int g   = (j >> 4) & 3;
        int hh  = ((j >> 6) << 4) | (j & 15);
        int r   = g * HIDN + hh;
        const float* src = (col < HIDN) ? (Wx + (int64_t)r * HIDN + col)
                                        : (Wh + (int64_t)r * HIDN + (col - HIDN));
        float4 v = *reinterpret_cast<const float4*>(src);
        ushort4 o;
        o.x = f2bf(v.x); o.y = f2bf(v.y); o.z = f2bf(v.z); o.w = f2bf(v.w);
        *reinterpret_cast<ushort4*>(Bp + (int64_t)j * K_DIM + col) = o;
    }
}

// ---------------- 256x256 GEMM, BK=32, 4-phase iter, 64KB LDS ----------------
// LDS: 4 regions of 16KB: region(buf,mat) = buf*16384 + mat*8192 (shorts).
// Region [256 rows][32 k] bf16 (64B rows); 16B-chunk swizzle slot ^= (row>>1)&3
// on BOTH pre-swizzled global source and ds_read (R3-verified: 0 conflicts).
// 2 blocks/CU (64KB LDS, 116 VGPR <= 128): inter-block overlap hides barriers.

__device__ __forceinline__ void stg1(unsigned short* dst, const unsigned short* src) {
    __builtin_amdgcn_global_load_lds(
        (const __attribute__((address_space(1))) unsigned int*)src,
        (__attribute__((address_space(3))) unsigned int*)dst, 16, 0, 0);
}

__global__ __launch_bounds__(512, 4) void lstm_gemm_kernel(
    const unsigned short* __restrict__ A, const unsigned short* __restrict__ Bp,
    const float* __restrict__ bx, const float* __restrict__ bh,
    const float* __restrict__ c0, float* __restrict__ out)
{
    __shared__ alignas(16) unsigned short smem[32768];   // 64 KB

    const int tid  = threadIdx.x;
    const int wid  = tid >> 6;
    const int lane = tid & 63;

    // 2D XCD chunking: grid 32(bm) x 16(bn) = 512; xcd owns 8bm x 8bn.
    const int bid = blockIdx.x;
    const int xcd = bid & 7;
    const int idx = bid >> 3;            // 0..63
    const int bm  = (xcd & 3) * 8 + (idx & 7);
    const int bn  = (xcd >> 2) * 8 + (idx >> 3);
    const int m0  = bm * BM;
    const int n0  = bn * BN;
    const int wm  = wid >> 2;            // 0..1
    const int wn  = wid & 3;             // 0..3

    const unsigned short* Ag = A  + (int64_t)m0 * K_DIM;
    const unsigned short* Bg = Bp + (int64_t)n0 * K_DIM;

    // staging: 512 threads x 16B = 8KB = half a region per STG2R half.
    // chunk c = tid: row(in half) = c>>2, slot = (c&3) ^ ((c>>3)&3)  [swizzle]
    const int64_t soffH0 = (int64_t)(tid >> 2) * K_DIM + (int64_t)(((tid & 3) ^ ((tid >> 3) & 3)) * 8);
    const int64_t soffH1 = soffH0 + (int64_t)128 * K_DIM;
    const int ldsH0 = wid * 512;                 // wave-uniform chunk base (shorts)
    const int ldsH1 = 4096 + wid * 512;

    // ds_read fragment offsets (region-relative, shorts)
    int offA[8], offB[4];
#pragma unroll
    for (int m = 0; m < 8; ++m) {
        const int row = wm * 128 + m * 16 + (lane & 15);
        offA[m] = row * 32 + (((lane >> 4) ^ (row >> 1)) & 3) * 8;
    }
#pragma unroll
    for (int n = 0; n < 4; ++n) {
        const int row = wn * 64 + n * 16 + (lane & 15);
        offB[n] = row * 32 + (((lane >> 4) ^ (row >> 1)) & 3) * 8;
    }

    f32x4 acc[8][4] = {};
    bf16x8 aF[4], bF[4];

#define REGP(buf, mat) (smem + (buf) * 16384 + (mat) * 8192)
#define LOAD_A(buf, mh) { \
    const unsigned short* r_ = REGP(buf, 0); \
    _Pragma("unroll") for (int m_ = 0; m_ < 4; ++m_) \
        aF[m_] = *reinterpret_cast<const bf16x8*>(r_ + offA[(mh) * 4 + m_]); }
#define LOAD_B(buf) { \
    const unsigned short* r_ = REGP(buf, 1); \
    _Pragma("unroll") for (int n_ = 0; n_ < 4; ++n_) \
        bF[n_] = *reinterpret_cast<const bf16x8*>(r_ + offB[n_]); }
#define MFMA16(mh) { \
    _Pragma("unroll") for (int m_ = 0; m_ < 4; ++m_) \
    _Pragma("unroll") for (int n_ = 0; n_ < 4; ++n_) \
        acc[(mh) * 4 + m_][n_] = __builtin_amdgcn_mfma_f32_16x16x32_bf16(aF[m_], bF[n_], acc[(mh) * 4 + m_][n_], 0, 0, 0); }
// stage BOTH halves of region (buf,mat) from tile base gt (= Mbase + T*32)
#define STG2R(buf, mat, gt) { \
    unsigned short* r_ = REGP(buf, mat); \
    stg1(r_ + ldsH0, (gt) + soffH0); \
    stg1(r_ + ldsH1, (gt) + soffH1); }
#define VM2() asm volatile("s_waitcnt vmcnt(2)" ::: "memory")
#define PH_PRE()  { __builtin_amdgcn_s_barrier(); \
                    __builtin_amdgcn_s_setprio(1); }
#define PH_POST() { __builtin_amdgcn_s_setprio(0); \
                    __builtin_amdgcn_s_barrier(); }

    // ---- prologue: t0 (buf0) B+A, t1 (buf1) B; vmcnt(2) -> t0 landed ----
    STG2R(0, 1, Bg);          // t0.B
    STG2R(0, 0, Ag);          // t0.A
    STG2R(1, 1, Bg + 32);     // t1.B
    asm volatile("s_waitcnt vmcnt(2)" ::: "memory");
    __builtin_amdgcn_s_barrier();

    // ---- main loop: iter i computes tiles 2i (buf0, ph1-2), 2i+1 (buf1, ph3-4) ----
    // stage slots: ph1: buf1A <- t(2i+1).A   (buf1A free since prev ph4)
    //              ph2: buf0B <- t(2i+2).B   (freed ph1); vmcnt(2) -> t(2i+1) ready
    //              ph3: buf0A <- t(2i+2).A   (freed ph2)
    //              ph4: buf1B <- t(2i+3).B   (freed ph3); vmcnt(2) -> t(2i+2) ready
    for (int i = 0; i < NITER - 1; ++i) {
        const unsigned short* At1 = Ag + (2 * i + 1) * 32;
        const unsigned short* At2 = Ag + (2 * i + 2) * 32;
        const unsigned short* Bt2 = Bg + (2 * i + 2) * 32;
        const unsigned short* Bt3 = Bg + (2 * i + 3) * 32;

        // ph1: t2i mh0
        LOAD_A(0, 0); LOAD_B(0);
        STG2R(1, 0, At1);
        PH_PRE(); MFMA16(0); PH_POST();
        // ph2: t2i mh1
        LOAD_A(0, 1);
        STG2R(0, 1, Bt2);
        VM2();
        PH_PRE(); MFMA16(1); PH_POST();
        // ph3: t(2i+1) mh0
        LOAD_A(1, 0); LOAD_B(1);
        STG2R(0, 0, At2);
        PH_PRE(); MFMA16(0); PH_POST();
        // ph4: t(2i+1) mh1
        LOAD_A(1, 1);
        STG2R(1, 1, Bt3);
        VM2();
        PH_PRE(); MFMA16(1); PH_POST();
    }

    // ---- final iter (tiles 62, 63): only t63.A left to stage ----
    {
        LOAD_A(0, 0); LOAD_B(0);
        STG2R(1, 0, Ag + 63 * 32);
        PH_PRE(); MFMA16(0); PH_POST();
        LOAD_A(0, 1);
        asm volatile("s_waitcnt vmcnt(0)" ::: "memory");   // t63 B+A retired
        PH_PRE(); MFMA16(1); PH_POST();
        LOAD_A(1, 0); LOAD_B(1);
        PH_PRE(); MFMA16(0); PH_POST();
        LOAD_A(1, 1);
        PH_PRE(); MFMA16(1);
        __builtin_amdgcn_s_setprio(0);
    }

    // ---- fused LSTM epilogue ----
    const int h = (n0 >> 2) + wn * 16 + (lane & 15);
    const float bi  = bx[h]            + bh[h];
    const float bff = bx[HIDN + h]     + bh[HIDN + h];
    const float bc  = bx[2 * HIDN + h] + bh[2 * HIDN + h];
    const float bo  = bx[3 * HIDN + h] + bh[3 * HIDN + h];

#pragma unroll
    for (int m = 0; m < 8; ++m) {
        const int rowb = m0 + wm * 128 + m * 16 + ((lane >> 4) << 2);
#pragma unroll
        for (int r = 0; r < 4; ++r) {
            const int row = rowb + r;
            const float gi = acc[m][0][r] + bi;
            const float gf = acc[m][1][r] + bff;
            const float gc = acc[m][2][r] + bc;
            const float go = acc[m][3][r] + bo;
            const float si = 1.f / (1.f + __expf(-gi));
            const float sf = 1.f / (1.f + __expf(-gf));
            const float tc = 1.f - 2.f / (__expf(2.f * gc) + 1.f);
            const float so = 1.f / (1.f + __expf(-go));
            const float c0v = c0[(int64_t)row * HIDN + h];
            const float c1 = sf * c0v + si * tc;
            const float th = 1.f - 2.f / (__expf(2.f * c1) + 1.f);
            out[(int64_t)row * HIDN + h] = so * th;                        // h1
            out[(int64_t)M_ROWS * HIDN + (int64_t)row * HIDN + h] = c1;    // c1
        }
    }
}

extern "C" void kernel_launch(void* const* d_in, const int* in_sizes, int n_in,
                              void* d_out, int out_size, void* d_ws, size_t ws_size,
                              hipStream_t stream) {
    const float* x  = (const float*)d_in[0];
    const float* h0 = (const float*)d_in[1];
    const float* c0 = (const float*)d_in[2];
    const float* Wx = (const float*)d_in[3];
    const float* bx = (const float*)d_in[4];
    const float* Wh = (const float*)d_in[5];
    const float* bh = (const float*)d_in[6];
    float* out = (float*)d_out;

    unsigned short* A = (unsigned short*)d_ws;                       // 33.5 MB
    unsigned short* B = A + (size_t)M_ROWS * K_DIM;                  // 16.8 MB

    pack_kernel<<<dim3(24576), dim3(256), 0, stream>>>(x, h0, Wx, Wh, A, B);
    lstm_gemm_kernel<<<dim3(512), dim3(512), 0, stream>>>(A, B, bx, bh, c0, out);
}

// Round 8
// 164.404 us; speedup vs baseline: 7.9837x; 7.9837x over previous
//
#include <hip/hip_runtime.h>
#include <hip/hip_bf16.h>
#include <stdint.h>

typedef __bf16 bf16x8 __attribute__((ext_vector_type(8)));
typedef float  f32x4  __attribute__((ext_vector_type(4)));

#define M_ROWS 8192
#define K_DIM  2048
#define HIDN   1024
#define BM 256
#define BN 256
#define BK 32
#define NTILES (K_DIM / BK)   /* 64 */
#define NITER  (NTILES / 2)   /* 32 */

__device__ __forceinline__ unsigned short f2bf(float f) {
    __hip_bfloat16 h = __float2bfloat16(f);
    return *reinterpret_cast<unsigned short*>(&h);
}

// ---------------- fused pack kernel (verified) ----------------
__global__ __launch_bounds__(256) void pack_kernel(const float* __restrict__ x,
                                                   const float* __restrict__ h0,
                                                   const float* __restrict__ Wx,
                                                   const float* __restrict__ Wh,
                                                   unsigned short* __restrict__ A,
                                                   unsigned short* __restrict__ Bp) {
    if (blockIdx.x < 16384) {
        int idx = blockIdx.x * 256 + threadIdx.x;
        int row = idx >> 9;
        int col = (idx & 511) << 2;
        const float* src = (col < HIDN) ? (x + (int64_t)row * HIDN + col)
                                        : (h0 + (int64_t)row * HIDN + (col - HIDN));
        float4 v = *reinterpret_cast<const float4*>(src);
        ushort4 o;
        o.x = f2bf(v.x); o.y = f2bf(v.y); o.z = f2bf(v.z); o.w = f2bf(v.w);
        *reinterpret_cast<ushort4*>(A + (int64_t)idx * 4) = o;
    } else {
        int idx = (blockIdx.x - 16384) * 256 + threadIdx.x;
        int j   = idx >> 9;
        int col = (idx & 511) << 2;
        int g   = (j >> 4) & 3;
        int hh  = ((j >> 6) << 4) | (j & 15);
        int r   = g * HIDN + hh;
        const float* src = (col < HIDN) ? (Wx + (int64_t)r * HIDN + col)
                                        : (Wh + (int64_t)r * HIDN + (col - HIDN));
        float4 v = *reinterpret_cast<const float4*>(src);
        ushort4 o;
        o.x = f2bf(v.x); o.y = f2bf(v.y); o.z = f2bf(v.z); o.w = f2bf(v.w);
        *reinterpret_cast<ushort4*>(Bp + (int64_t)j * K_DIM + col) = o;
    }
}

// ---------------- 256x256 GEMM, BK=32, 4-phase iter, 64KB LDS ----------------
// LDS: 4 regions of 16KB: region(buf,mat) = buf*16384 + mat*8192 (shorts).
// Region [256 rows][32 k] bf16 (64B rows); 16B-chunk swizzle slot ^= (row>>1)&3
// on BOTH pre-swizzled global source and ds_read (R3-verified: 0 conflicts).
// 2 blocks/CU arise NATURALLY: 116 VGPR <= 128 (16 waves/CU per m69) and
// 2 x 64KB LDS <= 160KB. Do NOT force via launch_bounds min-waves (R7: a
// (512,4) bound capped the unified VGPR/AGPR file at 64+64 -> acc spilled,
// 6.5 GB scratch traffic, 9x regression).

__device__ __forceinline__ void stg1(unsigned short* dst, const unsigned short* src) {
    __builtin_amdgcn_global_load_lds(
        (const __attribute__((address_space(1))) unsigned int*)src,
        (__attribute__((address_space(3))) unsigned int*)dst, 16, 0, 0);
}

__global__ __launch_bounds__(512, 2) void lstm_gemm_kernel(
    const unsigned short* __restrict__ A, const unsigned short* __restrict__ Bp,
    const float* __restrict__ bx, const float* __restrict__ bh,
    const float* __restrict__ c0, float* __restrict__ out)
{
    __shared__ alignas(16) unsigned short smem[32768];   // 64 KB

    const int tid  = threadIdx.x;
    const int wid  = tid >> 6;
    const int lane = tid & 63;

    // 2D XCD chunking: grid 32(bm) x 16(bn) = 512; xcd owns 8bm x 8bn.
    const int bid = blockIdx.x;
    const int xcd = bid & 7;
    const int idx = bid >> 3;            // 0..63
    const int bm  = (xcd & 3) * 8 + (idx & 7);
    const int bn  = (xcd >> 2) * 8 + (idx >> 3);
    const int m0  = bm * BM;
    const int n0  = bn * BN;
    const int wm  = wid >> 2;            // 0..1
    const int wn  = wid & 3;             // 0..3

    const unsigned short* Ag = A  + (int64_t)m0 * K_DIM;
    const unsigned short* Bg = Bp + (int64_t)n0 * K_DIM;

    // staging: 512 threads x 16B = 8KB = half a region per STG2R half.
    // chunk c = tid: row(in half) = c>>2, slot = (c&3) ^ ((c>>3)&3)  [swizzle]
    const int64_t soffH0 = (int64_t)(tid >> 2) * K_DIM + (int64_t)(((tid & 3) ^ ((tid >> 3) & 3)) * 8);
    const int64_t soffH1 = soffH0 + (int64_t)128 * K_DIM;
    const int ldsH0 = wid * 512;                 // wave-uniform chunk base (shorts)
    const int ldsH1 = 4096 + wid * 512;

    // ds_read fragment offsets (region-relative, shorts)
    int offA[8], offB[4];
#pragma unroll
    for (int m = 0; m < 8; ++m) {
        const int row = wm * 128 + m * 16 + (lane & 15);
        offA[m] = row * 32 + (((lane >> 4) ^ (row >> 1)) & 3) * 8;
    }
#pragma unroll
    for (int n = 0; n < 4; ++n) {
        const int row = wn * 64 + n * 16 + (lane & 15);
        offB[n] = row * 32 + (((lane >> 4) ^ (row >> 1)) & 3) * 8;
    }

    f32x4 acc[8][4] = {};
    bf16x8 aF[4], bF[4];

#define REGP(buf, mat) (smem + (buf) * 16384 + (mat) * 8192)
#define LOAD_A(buf, mh) { \
    const unsigned short* r_ = REGP(buf, 0); \
    _Pragma("unroll") for (int m_ = 0; m_ < 4; ++m_) \
        aF[m_] = *reinterpret_cast<const bf16x8*>(r_ + offA[(mh) * 4 + m_]); }
#define LOAD_B(buf) { \
    const unsigned short* r_ = REGP(buf, 1); \
    _Pragma("unroll") for (int n_ = 0; n_ < 4; ++n_) \
        bF[n_] = *reinterpret_cast<const bf16x8*>(r_ + offB[n_]); }
#define MFMA16(mh) { \
    _Pragma("unroll") for (int m_ = 0; m_ < 4; ++m_) \
    _Pragma("unroll") for (int n_ = 0; n_ < 4; ++n_) \
        acc[(mh) * 4 + m_][n_] = __builtin_amdgcn_mfma_f32_16x16x32_bf16(aF[m_], bF[n_], acc[(mh) * 4 + m_][n_], 0, 0, 0); }
// stage BOTH halves of region (buf,mat) from tile base gt (= Mbase + T*32)
#define STG2R(buf, mat, gt) { \
    unsigned short* r_ = REGP(buf, mat); \
    stg1(r_ + ldsH0, (gt) + soffH0); \
    stg1(r_ + ldsH1, (gt) + soffH1); }
#define VM2() asm volatile("s_waitcnt vmcnt(2)" ::: "memory")
#define PH_PRE()  { __builtin_amdgcn_s_barrier(); \
                    __builtin_amdgcn_s_setprio(1); }
#define PH_POST() { __builtin_amdgcn_s_setprio(0); \
                    __builtin_amdgcn_s_barrier(); }

    // ---- prologue: t0 (buf0) B+A, t1 (buf1) B; vmcnt(2) -> t0 landed ----
    STG2R(0, 1, Bg);          // t0.B
    STG2R(0, 0, Ag);          // t0.A
    STG2R(1, 1, Bg + 32);     // t1.B
    asm volatile("s_waitcnt vmcnt(2)" ::: "memory");
    __builtin_amdgcn_s_barrier();

    // ---- main loop: iter i computes tiles 2i (buf0, ph1-2), 2i+1 (buf1, ph3-4) ----
    // stage slots: ph1: buf1A <- t(2i+1).A   (buf1A free since prev ph4)
    //              ph2: buf0B <- t(2i+2).B   (freed ph1); vmcnt(2) -> t(2i+1) ready
    //              ph3: buf0A <- t(2i+2).A   (freed ph2)
    //              ph4: buf1B <- t(2i+3).B   (freed ph3); vmcnt(2) -> t(2i+2) ready
    for (int i = 0; i < NITER - 1; ++i) {
        const unsigned short* At1 = Ag + (2 * i + 1) * 32;
        const unsigned short* At2 = Ag + (2 * i + 2) * 32;
        const unsigned short* Bt2 = Bg + (2 * i + 2) * 32;
        const unsigned short* Bt3 = Bg + (2 * i + 3) * 32;

        // ph1: t2i mh0
        LOAD_A(0, 0); LOAD_B(0);
        STG2R(1, 0, At1);
        PH_PRE(); MFMA16(0); PH_POST();
        // ph2: t2i mh1
        LOAD_A(0, 1);
        STG2R(0, 1, Bt2);
        VM2();
        PH_PRE(); MFMA16(1); PH_POST();
        // ph3: t(2i+1) mh0
        LOAD_A(1, 0); LOAD_B(1);
        STG2R(0, 0, At2);
        PH_PRE(); MFMA16(0); PH_POST();
        // ph4: t(2i+1) mh1
        LOAD_A(1, 1);
        STG2R(1, 1, Bt3);
        VM2();
        PH_PRE(); MFMA16(1); PH_POST();
    }

    // ---- final iter (tiles 62, 63): only t63.A left to stage ----
    {
        LOAD_A(0, 0); LOAD_B(0);
        STG2R(1, 0, Ag + 63 * 32);
        PH_PRE(); MFMA16(0); PH_POST();
        LOAD_A(0, 1);
        asm volatile("s_waitcnt vmcnt(0)" ::: "memory");   // t63 B+A retired
        PH_PRE(); MFMA16(1); PH_POST();
        LOAD_A(1, 0); LOAD_B(1);
        PH_PRE(); MFMA16(0); PH_POST();
        LOAD_A(1, 1);
        PH_PRE(); MFMA16(1);
        __builtin_amdgcn_s_setprio(0);
    }

    // ---- fused LSTM epilogue ----
    const int h = (n0 >> 2) + wn * 16 + (lane & 15);
    const float bi  = bx[h]            + bh[h];
    const float bff = bx[HIDN + h]     + bh[HIDN + h];
    const float bc  = bx[2 * HIDN + h] + bh[2 * HIDN + h];
    const float bo  = bx[3 * HIDN + h] + bh[3 * HIDN + h];

#pragma unroll
    for (int m = 0; m < 8; ++m) {
        const int rowb = m0 + wm * 128 + m * 16 + ((lane >> 4) << 2);
#pragma unroll
        for (int r = 0; r < 4; ++r) {
            const int row = rowb + r;
            const float gi = acc[m][0][r] + bi;
            const float gf = acc[m][1][r] + bff;
            const float gc = acc[m][2][r] + bc;
            const float go = acc[m][3][r] + bo;
            const float si = 1.f / (1.f + __expf(-gi));
            const float sf = 1.f / (1.f + __expf(-gf));
            const float tc = 1.f - 2.f / (__expf(2.f * gc) + 1.f);
            const float so = 1.f / (1.f + __expf(-go));
            const float c0v = c0[(int64_t)row * HIDN + h];
            const float c1 = sf * c0v + si * tc;
            const float th = 1.f - 2.f / (__expf(2.f * c1) + 1.f);
            out[(int64_t)row * HIDN + h] = so * th;                        // h1
            out[(int64_t)M_ROWS * HIDN + (int64_t)row * HIDN + h] = c1;    // c1
        }
    }
}

extern "C" void kernel_launch(void* const* d_in, const int* in_sizes, int n_in,
                              void* d_out, int out_size, void* d_ws, size_t ws_size,
                              hipStream_t stream) {
    const float* x  = (const float*)d_in[0];
    const float* h0 = (const float*)d_in[1];
    const float* c0 = (const float*)d_in[2];
    const float* Wx = (const float*)d_in[3];
    const float* bx = (const float*)d_in[4];
    const float* Wh = (const float*)d_in[5];
    const float* bh = (const float*)d_in[6];
    float* out = (float*)d_out;

    unsigned short* A = (unsigned short*)d_ws;                       // 33.5 MB
    unsigned short* B = A + (size_t)M_ROWS * K_DIM;                  // 16.8 MB

    pack_kernel<<<dim3(24576), dim3(256), 0, stream>>>(x, h0, Wx, Wh, A, B);
    lstm_gemm_kernel<<<dim3(512), dim3(512), 0, stream>>>(A, B, bx, bh, c0, out);
}

// Round 9
// 163.871 us; speedup vs baseline: 8.0096x; 1.0033x over previous
//
#include <hip/hip_runtime.h>
#include <hip/hip_bf16.h>
#include <stdint.h>

typedef __bf16 bf16x8 __attribute__((ext_vector_type(8)));
typedef float  f32x4  __attribute__((ext_vector_type(4)));

#define M_ROWS 8192
#define K_DIM  2048
#define HIDN   1024
#define BM 256
#define BN 256
#define BK 64
#define NTILES (K_DIM / BK)   /* 32 */
#define NITER  (NTILES / 2)   /* 16 */

__device__ __forceinline__ unsigned short f2bf(float f) {
    __hip_bfloat16 h = __float2bfloat16(f);
    return *reinterpret_cast<unsigned short*>(&h);
}

// ---------------- fused pack kernel (verified) ----------------
__global__ __launch_bounds__(256) void pack_kernel(const float* __restrict__ x,
                                                   const float* __restrict__ h0,
                                                   const float* __restrict__ Wx,
                                                   const float* __restrict__ Wh,
                                                   unsigned short* __restrict__ A,
                                                   unsigned short* __restrict__ Bp) {
    if (blockIdx.x < 16384) {
        int idx = blockIdx.x * 256 + threadIdx.x;
        int row = idx >> 9;
        int col = (idx & 511) << 2;
        const float* src = (col < HIDN) ? (x + (int64_t)row * HIDN + col)
                                        : (h0 + (int64_t)row * HIDN + (col - HIDN));
        float4 v = *reinterpret_cast<const float4*>(src);
        ushort4 o;
        o.x = f2bf(v.x); o.y = f2bf(v.y); o.z = f2bf(v.z); o.w = f2bf(v.w);
        *reinterpret_cast<ushort4*>(A + (int64_t)idx * 4) = o;
    } else {
        int idx = (blockIdx.x - 16384) * 256 + threadIdx.x;
        int j   = idx >> 9;
        int col = (idx & 511) << 2;
        int g   = (j >> 4) & 3;
        int hh  = ((j >> 6) << 4) | (j & 15);
        int r   = g * HIDN + hh;
        const float* src = (col < HIDN) ? (Wx + (int64_t)r * HIDN + col)
                                        : (Wh + (int64_t)r * HIDN + (col - HIDN));
        float4 v = *reinterpret_cast<const float4*>(src);
        ushort4 o;
        o.x = f2bf(v.x); o.y = f2bf(v.y); o.z = f2bf(v.z); o.w = f2bf(v.w);
        *reinterpret_cast<ushort4*>(Bp + (int64_t)j * K_DIM + col) = o;
    }
}

// ---------------- 256x256 8-phase GEMM + register prefetch ----------------
// R6-verified machinery (swizzle: 0 conflicts; vmcnt schedule; stage order
// UNCHANGED) + ping-pong fragment sets: phase p issues ds_reads for phase
// p+1 before its begin barrier; MFMA runs on regs loaded in phase p-1, so
// LDS reads drain under the MFMA cluster instead of serializing before it.

__device__ __forceinline__ void stg2(unsigned short* r_, const unsigned short* gt,
                                     int64_t soff0, int64_t soff1, int l0, int l1) {
    __builtin_amdgcn_global_load_lds(
        (const __attribute__((address_space(1))) unsigned int*)(gt + soff0),
        (__attribute__((address_space(3))) unsigned int*)(r_ + l0), 16, 0, 0);
    __builtin_amdgcn_global_load_lds(
        (const __attribute__((address_space(1))) unsigned int*)(gt + soff1),
        (__attribute__((address_space(3))) unsigned int*)(r_ + l1), 16, 0, 0);
}

__global__ __launch_bounds__(512, 2) void lstm_gemm_kernel(
    const unsigned short* __restrict__ A, const unsigned short* __restrict__ Bp,
    const float* __restrict__ bx, const float* __restrict__ bh,
    const float* __restrict__ c0, float* __restrict__ out)
{
    __shared__ alignas(16) unsigned short smem[65536];   // 128 KB

    const int tid  = threadIdx.x;
    const int wid  = tid >> 6;
    const int lane = tid & 63;

    // 2D XCD chunking: grid 32(bm) x 16(bn) = 512; xcd owns 8bm x 8bn.
    const int bid = blockIdx.x;
    const int xcd = bid & 7;
    const int idx = bid >> 3;            // 0..63
    const int bm  = (xcd & 3) * 8 + (idx & 7);
    const int bn  = (xcd >> 2) * 8 + (idx >> 3);
    const int m0  = bm * BM;
    const int n0  = bn * BN;
    const int wm  = wid >> 2;            // 0..1
    const int wn  = wid & 3;             // 0..3

    const unsigned short* Ag = A  + (int64_t)m0 * K_DIM;
    const unsigned short* Bg = Bp + (int64_t)n0 * K_DIM;

    // staging constants: chunk c = ld*512 + wid*64 + lane; row = c>>2
    const int c0_ = wid * 64 + lane;
    const int c1_ = 512 + c0_;
    const int64_t soff0 = (int64_t)(c0_ >> 2) * K_DIM + (int64_t)((((c0_ & 3) ^ ((c0_ >> 3) & 3))) * 8);
    const int64_t soff1 = (int64_t)(c1_ >> 2) * K_DIM + (int64_t)((((c1_ & 3) ^ ((c1_ >> 3) & 3))) * 8);
    const int l0 = (c0_ & ~63) * 8;
    const int l1 = (c1_ & ~63) * 8;

    // ds_read fragment offsets (region-relative, shorts)
    int offA[8], offB[4];
#pragma unroll
    for (int m = 0; m < 8; ++m) {
        const int row = wm * 128 + m * 16 + (lane & 15);
        offA[m] = row * 32 + (((lane >> 4) ^ (row >> 1)) & 3) * 8;
    }
#pragma unroll
    for (int n = 0; n < 4; ++n) {
        const int row = wn * 64 + n * 16 + (lane & 15);
        offB[n] = row * 32 + (((lane >> 4) ^ (row >> 1)) & 3) * 8;
    }

    f32x4 acc[8][4] = {};
    bf16x8 aX[4], aY[4], bX[4], bY[4];   // ping-pong fragment sets

#define REGP(buf, mat, kh) (smem + (buf) * 32768 + (mat) * 16384 + (kh) * 8192)
#define LOAD_AS(S, buf, kh, mh) { \
    const unsigned short* r_ = REGP(buf, 0, kh); \
    _Pragma("unroll") for (int m_ = 0; m_ < 4; ++m_) \
        S[m_] = *reinterpret_cast<const bf16x8*>(r_ + offA[(mh) * 4 + m_]); }
#define LOAD_BS(S, buf, kh) { \
    const unsigned short* r_ = REGP(buf, 1, kh); \
    _Pragma("unroll") for (int n_ = 0; n_ < 4; ++n_) \
        S[n_] = *reinterpret_cast<const bf16x8*>(r_ + offB[n_]); }
#define MFMA16S(aS, bS, mh) { \
    _Pragma("unroll") for (int m_ = 0; m_ < 4; ++m_) \
    _Pragma("unroll") for (int n_ = 0; n_ < 4; ++n_) \
        acc[(mh) * 4 + m_][n_] = __builtin_amdgcn_mfma_f32_16x16x32_bf16(aS[m_], bS[n_], acc[(mh) * 4 + m_][n_], 0, 0, 0); }
#define STG(buf, mat, kh, gt) stg2(REGP(buf, mat, kh), (gt), soff0, soff1, l0, l1)
#define VM6() asm volatile("s_waitcnt vmcnt(6)" ::: "memory")
#define PH_PRE()  { __builtin_amdgcn_s_barrier(); \
                    __builtin_amdgcn_s_setprio(1); }
#define PH_POST() { __builtin_amdgcn_s_setprio(0); \
                    __builtin_amdgcn_s_barrier(); }

    // ---- prologue: tile0 all 4 halves, vmcnt(4), tile1 first 3 halves, vmcnt(6) ----
    STG(0, 1, 0, Bg);            // t0.B-kh0
    STG(0, 0, 0, Ag);            // t0.A-kh0
    STG(0, 1, 1, Bg + 32);       // t0.B-kh1
    STG(0, 0, 1, Ag + 32);       // t0.A-kh1
    asm volatile("s_waitcnt vmcnt(4)" ::: "memory");
    STG(1, 1, 0, Bg + 64);       // t1.B-kh0
    STG(1, 0, 0, Ag + 64);       // t1.A-kh0
    STG(1, 1, 1, Bg + 96);       // t1.B-kh1
    asm volatile("s_waitcnt vmcnt(6)" ::: "memory");
    __builtin_amdgcn_s_barrier();

    // pre-load P1's fragments (buf0 kh0)
    LOAD_AS(aX, 0, 0, 0); LOAD_BS(bX, 0, 0);

    // ---- main loop: iter i computes tiles 2i (buf0) and 2i+1 (buf1) ----
    // Each phase: prefetch regs for NEXT phase; STG (order unchanged from R6);
    // barrier; MFMA on regs loaded LAST phase; barrier.
    for (int i = 0; i < NITER - 1; ++i) {
        const unsigned short* At1 = Ag + (2 * i + 1) * 64;
        const unsigned short* At2 = Ag + (2 * i + 2) * 64;
        const unsigned short* At3 = Ag + (2 * i + 3) * 64;
        const unsigned short* Bt2 = Bg + (2 * i + 2) * 64;
        const unsigned short* Bt3 = Bg + (2 * i + 3) * 64;

        // P1: compute (0,kh0,mh0) on aX/bX; prefetch aY <- (0,kh0,mh1)
        LOAD_AS(aY, 0, 0, 1);
        STG(1, 0, 1, At1 + 32);
        PH_PRE(); MFMA16S(aX, bX, 0); PH_POST();
        // P2: compute (0,kh0,mh1) on aY/bX; prefetch aX,bY <- (0,kh1,mh0)
        LOAD_AS(aX, 0, 1, 0); LOAD_BS(bY, 0, 1);
        STG(0, 1, 0, Bt2);
        PH_PRE(); MFMA16S(aY, bX, 1); PH_POST();
        // P3: compute (0,kh1,mh0) on aX/bY; prefetch aY <- (0,kh1,mh1)
        LOAD_AS(aY, 0, 1, 1);
        STG(0, 0, 0, At2);
        PH_PRE(); MFMA16S(aX, bY, 0); PH_POST();
        // P4: compute (0,kh1,mh1) on aY/bY; VM6 -> buf1 (t2i+1) landed;
        //     prefetch aX,bX <- (1,kh0,mh0) AFTER the wait
        STG(0, 1, 1, Bt2 + 32);
        VM6();
        LOAD_AS(aX, 1, 0, 0); LOAD_BS(bX, 1, 0);
        PH_PRE(); MFMA16S(aY, bY, 1); PH_POST();
        // P5: compute (1,kh0,mh0) on aX/bX; prefetch aY <- (1,kh0,mh1)
        LOAD_AS(aY, 1, 0, 1);
        STG(0, 0, 1, At2 + 32);
        PH_PRE(); MFMA16S(aX, bX, 0); PH_POST();
        // P6: compute (1,kh0,mh1) on aY/bX; prefetch aX,bY <- (1,kh1,mh0)
        LOAD_AS(aX, 1, 1, 0); LOAD_BS(bY, 1, 1);
        STG(1, 1, 0, Bt3);
        PH_PRE(); MFMA16S(aY, bX, 1); PH_POST();
        // P7: compute (1,kh1,mh0) on aX/bY; prefetch aY <- (1,kh1,mh1)
        LOAD_AS(aY, 1, 1, 1);
        STG(1, 0, 0, At3);
        PH_PRE(); MFMA16S(aX, bY, 0); PH_POST();
        // P8: compute (1,kh1,mh1) on aY/bY; VM6 -> buf0 (t2i+2) landed;
        //     prefetch aX,bX <- next iter (0,kh0,mh0) AFTER the wait
        STG(1, 1, 1, Bt3 + 32);
        VM6();
        LOAD_AS(aX, 0, 0, 0); LOAD_BS(bX, 0, 0);
        PH_PRE(); MFMA16S(aY, bY, 1); PH_POST();
    }

    // ---- final iteration (tiles 30, 31): only t31.A-kh1 left to stage ----
    {
        LOAD_AS(aY, 0, 0, 1);
        STG(1, 0, 1, Ag + 31 * 64 + 32);
        PH_PRE(); MFMA16S(aX, bX, 0); PH_POST();
        LOAD_AS(aX, 0, 1, 0); LOAD_BS(bY, 0, 1);
        PH_PRE(); MFMA16S(aY, bX, 1); PH_POST();
        LOAD_AS(aY, 0, 1, 1);
        PH_PRE(); MFMA16S(aX, bY, 0); PH_POST();
        asm volatile("s_waitcnt vmcnt(0)" ::: "memory");   // buf1 (t31) fully landed
        LOAD_AS(aX, 1, 0, 0); LOAD_BS(bX, 1, 0);
        PH_PRE(); MFMA16S(aY, bY, 1); PH_POST();
        LOAD_AS(aY, 1, 0, 1);
        PH_PRE(); MFMA16S(aX, bX, 0); PH_POST();
        LOAD_AS(aX, 1, 1, 0); LOAD_BS(bY, 1, 1);
        PH_PRE(); MFMA16S(aY, bX, 1); PH_POST();
        LOAD_AS(aY, 1, 1, 1);
        PH_PRE(); MFMA16S(aX, bY, 0); PH_POST();
        PH_PRE(); MFMA16S(aY, bY, 1);
        __builtin_amdgcn_s_setprio(0);
    }

    // ---- fused LSTM epilogue ----
    const int h = (n0 >> 2) + wn * 16 + (lane & 15);
    const float bi  = bx[h]            + bh[h];
    const float bff = bx[HIDN + h]     + bh[HIDN + h];
    const float bc  = bx[2 * HIDN + h] + bh[2 * HIDN + h];
    const float bo  = bx[3 * HIDN + h] + bh[3 * HIDN + h];

#pragma unroll
    for (int m = 0; m < 8; ++m) {
        const int rowb = m0 + wm * 128 + m * 16 + ((lane >> 4) << 2);
#pragma unroll
        for (int r = 0; r < 4; ++r) {
            const int row = rowb + r;
            const float gi = acc[m][0][r] + bi;
            const float gf = acc[m][1][r] + bff;
            const float gc = acc[m][2][r] + bc;
            const float go = acc[m][3][r] + bo;
            const float si = 1.f / (1.f + __expf(-gi));
            const float sf = 1.f / (1.f + __expf(-gf));
            const float tc = 1.f - 2.f / (__expf(2.f * gc) + 1.f);
            const float so = 1.f / (1.f + __expf(-go));
            const float c0v = c0[(int64_t)row * HIDN + h];
            const float c1 = sf * c0v + si * tc;
            const float th = 1.f - 2.f / (__expf(2.f * c1) + 1.f);
            out[(int64_t)row * HIDN + h] = so * th;                        // h1
            out[(int64_t)M_ROWS * HIDN + (int64_t)row * HIDN + h] = c1;    // c1
        }
    }
}

extern "C" void kernel_launch(void* const* d_in, const int* in_sizes, int n_in,
                              void* d_out, int out_size, void* d_ws, size_t ws_size,
                              hipStream_t stream) {
    const float* x  = (const float*)d_in[0];
    const float* h0 = (const float*)d_in[1];
    const float* c0 = (const float*)d_in[2];
    const float* Wx = (const float*)d_in[3];
    const float* bx = (const float*)d_in[4];
    const float* Wh = (const float*)d_in[5];
    const float* bh = (const float*)d_in[6];
    float* out = (float*)d_out;

    unsigned short* A = (unsigned short*)d_ws;                       // 33.5 MB
    unsigned short* B = A + (size_t)M_ROWS * K_DIM;                  // 16.8 MB

    pack_kernel<<<dim3(24576), dim3(256), 0, stream>>>(x, h0, Wx, Wh, A, B);
    lstm_gemm_kernel<<<dim3(512), dim3(512), 0, stream>>>(A, B, bx, bh, c0, out);
}

// Round 10
// 158.764 us; speedup vs baseline: 8.2673x; 1.0322x over previous
//
#include <hip/hip_runtime.h>
#include <hip/hip_bf16.h>
#include <stdint.h>

typedef __bf16 bf16x8 __attribute__((ext_vector_type(8)));
typedef float  f32x4  __attribute__((ext_vector_type(4)));

#define M_ROWS 8192
#define K_DIM  2048
#define HIDN   1024
#define BM 256
#define BN 256
#define BK 64
#define NTILES (K_DIM / BK)   /* 32 */
#define NITER  (NTILES / 2)   /* 16 */

__device__ __forceinline__ unsigned short f2bf(float f) {
    __hip_bfloat16 h = __float2bfloat16(f);
    return *reinterpret_cast<unsigned short*>(&h);
}

// ---------------- fused pack kernel (verified) ----------------
__global__ __launch_bounds__(256) void pack_kernel(const float* __restrict__ x,
                                                   const float* __restrict__ h0,
                                                   const float* __restrict__ Wx,
                                                   const float* __restrict__ Wh,
                                                   unsigned short* __restrict__ A,
                                                   unsigned short* __restrict__ Bp) {
    if (blockIdx.x < 16384) {
        int idx = blockIdx.x * 256 + threadIdx.x;
        int row = idx >> 9;
        int col = (idx & 511) << 2;
        const float* src = (col < HIDN) ? (x + (int64_t)row * HIDN + col)
                                        : (h0 + (int64_t)row * HIDN + (col - HIDN));
        float4 v = *reinterpret_cast<const float4*>(src);
        ushort4 o;
        o.x = f2bf(v.x); o.y = f2bf(v.y); o.z = f2bf(v.z); o.w = f2bf(v.w);
        *reinterpret_cast<ushort4*>(A + (int64_t)idx * 4) = o;
    } else {
        int idx = (blockIdx.x - 16384) * 256 + threadIdx.x;
        int j   = idx >> 9;
        int col = (idx & 511) << 2;
        int g   = (j >> 4) & 3;
        int hh  = ((j >> 6) << 4) | (j & 15);
        int r   = g * HIDN + hh;
        const float* src = (col < HIDN) ? (Wx + (int64_t)r * HIDN + col)
                                        : (Wh + (int64_t)r * HIDN + (col - HIDN));
        float4 v = *reinterpret_cast<const float4*>(src);
        ushort4 o;
        o.x = f2bf(v.x); o.y = f2bf(v.y); o.z = f2bf(v.z); o.w = f2bf(v.w);
        *reinterpret_cast<ushort4*>(Bp + (int64_t)j * K_DIM + col) = o;
    }
}

// ---------- 256x256 8-phase GEMM, SINGLE barrier per phase ----------
// R6 machinery (swizzle verified 0-conflict; STG issue order and vmcnt
// counting IDENTICAL to R6). Phase block:
//   [ ds_reads (prefetch next phase / own ops after a VM-barrier) ;
//     STG ; (VM6 at P4/P8) ; lgkmcnt(0) ; s_barrier ; setprio1 ; MFMA ; setprio0 ]
// Safety proof sketch:
//  WAR: lgkmcnt(0) before barrier_q drains all reads issued in block_q, so a
//   STG issued after barrier_q may overwrite any region last-read-issued <= q.
//   All STG targets here have last-read-issue <= q-1.
//  RAW: first reads of a newly staged buffer are placed in the block AFTER the
//   covering VM6+barrier (P5 reads buf1 after P4's VM6+bar; P1 reads buf0 after
//   P8's VM6+bar) -> cross-wave landing guaranteed (fixes R9's latent race).

__device__ __forceinline__ void stg2(unsigned short* r_, const unsigned short* gt,
                                     int64_t soff0, int64_t soff1, int l0, int l1) {
    __builtin_amdgcn_global_load_lds(
        (const __attribute__((address_space(1))) unsigned int*)(gt + soff0),
        (__attribute__((address_space(3))) unsigned int*)(r_ + l0), 16, 0, 0);
    __builtin_amdgcn_global_load_lds(
        (const __attribute__((address_space(1))) unsigned int*)(gt + soff1),
        (__attribute__((address_space(3))) unsigned int*)(r_ + l1), 16, 0, 0);
}

__global__ __launch_bounds__(512, 2) void lstm_gemm_kernel(
    const unsigned short* __restrict__ A, const unsigned short* __restrict__ Bp,
    const float* __restrict__ bx, const float* __restrict__ bh,
    const float* __restrict__ c0, float* __restrict__ out)
{
    __shared__ alignas(16) unsigned short smem[65536];   // 128 KB

    const int tid  = threadIdx.x;
    const int wid  = tid >> 6;
    const int lane = tid & 63;

    // 2D XCD chunking: grid 32(bm) x 16(bn) = 512; xcd owns 8bm x 8bn.
    const int bid = blockIdx.x;
    const int xcd = bid & 7;
    const int idx = bid >> 3;            // 0..63
    const int bm  = (xcd & 3) * 8 + (idx & 7);
    const int bn  = (xcd >> 2) * 8 + (idx >> 3);
    const int m0  = bm * BM;
    const int n0  = bn * BN;
    const int wm  = wid >> 2;            // 0..1
    const int wn  = wid & 3;             // 0..3

    const unsigned short* Ag = A  + (int64_t)m0 * K_DIM;
    const unsigned short* Bg = Bp + (int64_t)n0 * K_DIM;

    // staging constants: chunk c = ld*512 + wid*64 + lane; row = c>>2
    const int c0_ = wid * 64 + lane;
    const int c1_ = 512 + c0_;
    const int64_t soff0 = (int64_t)(c0_ >> 2) * K_DIM + (int64_t)((((c0_ & 3) ^ ((c0_ >> 3) & 3))) * 8);
    const int64_t soff1 = (int64_t)(c1_ >> 2) * K_DIM + (int64_t)((((c1_ & 3) ^ ((c1_ >> 3) & 3))) * 8);
    const int l0 = (c0_ & ~63) * 8;
    const int l1 = (c1_ & ~63) * 8;

    // ds_read fragment offsets (region-relative, shorts)
    int offA[8], offB[4];
#pragma unroll
    for (int m = 0; m < 8; ++m) {
        const int row = wm * 128 + m * 16 + (lane & 15);
        offA[m] = row * 32 + (((lane >> 4) ^ (row >> 1)) & 3) * 8;
    }
#pragma unroll
    for (int n = 0; n < 4; ++n) {
        const int row = wn * 64 + n * 16 + (lane & 15);
        offB[n] = row * 32 + (((lane >> 4) ^ (row >> 1)) & 3) * 8;
    }

    f32x4 acc[8][4] = {};
    bf16x8 aX[4], aY[4], bX[4], bY[4];   // aX: mh0 frags, aY: mh1; bX/bY: kh ping-pong

#define REGP(buf, mat, kh) (smem + (buf) * 32768 + (mat) * 16384 + (kh) * 8192)
#define LOAD_AS(S, buf, kh, mh) { \
    const unsigned short* r_ = REGP(buf, 0, kh); \
    _Pragma("unroll") for (int m_ = 0; m_ < 4; ++m_) \
        S[m_] = *reinterpret_cast<const bf16x8*>(r_ + offA[(mh) * 4 + m_]); }
#define LOAD_BS(S, buf, kh) { \
    const unsigned short* r_ = REGP(buf, 1, kh); \
    _Pragma("unroll") for (int n_ = 0; n_ < 4; ++n_) \
        S[n_] = *reinterpret_cast<const bf16x8*>(r_ + offB[n_]); }
#define MFMA16S(aS, bS, mh) { \
    _Pragma("unroll") for (int m_ = 0; m_ < 4; ++m_) \
    _Pragma("unroll") for (int n_ = 0; n_ < 4; ++n_) \
        acc[(mh) * 4 + m_][n_] = __builtin_amdgcn_mfma_f32_16x16x32_bf16(aS[m_], bS[n_], acc[(mh) * 4 + m_][n_], 0, 0, 0); }
#define STG(buf, mat, kh, gt) stg2(REGP(buf, mat, kh), (gt), soff0, soff1, l0, l1)
#define VM6() asm volatile("s_waitcnt vmcnt(6)" ::: "memory")
// single barrier per phase: drain own ds_reads, sync, boost MFMA
#define SB()  { asm volatile("s_waitcnt lgkmcnt(0)" ::: "memory"); \
                __builtin_amdgcn_s_barrier(); \
                __builtin_amdgcn_s_setprio(1); }
#define SE()  { __builtin_amdgcn_s_setprio(0); }

    // ---- prologue (STG order identical to R6) ----
    STG(0, 1, 0, Bg);            // t0.B-kh0
    STG(0, 0, 0, Ag);            // t0.A-kh0
    STG(0, 1, 1, Bg + 32);       // t0.B-kh1
    STG(0, 0, 1, Ag + 32);       // t0.A-kh1
    asm volatile("s_waitcnt vmcnt(4)" ::: "memory");
    STG(1, 1, 0, Bg + 64);       // t1.B-kh0
    STG(1, 0, 0, Ag + 64);       // t1.A-kh0
    STG(1, 1, 1, Bg + 96);       // t1.B-kh1
    asm volatile("s_waitcnt vmcnt(6)" ::: "memory");
    __builtin_amdgcn_s_barrier();

    // ---- main loop: iter i computes tiles 2i (buf0) and 2i+1 (buf1) ----
    for (int i = 0; i < NITER - 1; ++i) {
        const unsigned short* At1 = Ag + (2 * i + 1) * 64;
        const unsigned short* At2 = Ag + (2 * i + 2) * 64;
        const unsigned short* At3 = Ag + (2 * i + 3) * 64;
        const unsigned short* Bt2 = Bg + (2 * i + 2) * 64;
        const unsigned short* Bt3 = Bg + (2 * i + 3) * 64;

        // P1: own ops (buf0-kh0, landed per P8's VM6+bar) + prefetch aY
        LOAD_AS(aX, 0, 0, 0); LOAD_BS(bX, 0, 0); LOAD_AS(aY, 0, 0, 1);
        STG(1, 0, 1, At1 + 32);
        SB(); MFMA16S(aX, bX, 0); SE();
        // P2: prefetch (0,kh1) ops
        LOAD_AS(aX, 0, 1, 0); LOAD_BS(bY, 0, 1);
        STG(0, 1, 0, Bt2);
        SB(); MFMA16S(aY, bX, 1); SE();
        // P3: prefetch aY (0,kh1,mh1)
        LOAD_AS(aY, 0, 1, 1);
        STG(0, 0, 0, At2);
        SB(); MFMA16S(aX, bY, 0); SE();
        // P4: VM6 -> buf1 (t2i+1) landed for all waves after this barrier
        STG(0, 1, 1, Bt2 + 32);
        VM6();
        SB(); MFMA16S(aY, bY, 1); SE();
        // P5: own ops (buf1-kh0) + prefetch aY
        LOAD_AS(aX, 1, 0, 0); LOAD_BS(bX, 1, 0); LOAD_AS(aY, 1, 0, 1);
        STG(0, 0, 1, At2 + 32);
        SB(); MFMA16S(aX, bX, 0); SE();
        // P6: prefetch (1,kh1)
        LOAD_AS(aX, 1, 1, 0); LOAD_BS(bY, 1, 1);
        STG(1, 1, 0, Bt3);
        SB(); MFMA16S(aY, bX, 1); SE();
        // P7: prefetch aY (1,kh1,mh1)
        LOAD_AS(aY, 1, 1, 1);
        STG(1, 0, 0, At3);
        SB(); MFMA16S(aX, bY, 0); SE();
        // P8: VM6 -> buf0 (t2i+2) landed after this barrier
        STG(1, 1, 1, Bt3 + 32);
        VM6();
        SB(); MFMA16S(aY, bY, 1); SE();
    }

    // ---- final iteration (tiles 30, 31): only t31.A-kh1 left to stage ----
    {
        LOAD_AS(aX, 0, 0, 0); LOAD_BS(bX, 0, 0); LOAD_AS(aY, 0, 0, 1);
        STG(1, 0, 1, Ag + 31 * 64 + 32);
        SB(); MFMA16S(aX, bX, 0); SE();
        LOAD_AS(aX, 0, 1, 0); LOAD_BS(bY, 0, 1);
        SB(); MFMA16S(aY, bX, 1); SE();
        LOAD_AS(aY, 0, 1, 1);
        SB(); MFMA16S(aX, bY, 0); SE();
        asm volatile("s_waitcnt vmcnt(0)" ::: "memory");   // t31 fully landed
        SB(); MFMA16S(aY, bY, 1); SE();
        LOAD_AS(aX, 1, 0, 0); LOAD_BS(bX, 1, 0); LOAD_AS(aY, 1, 0, 1);
        SB(); MFMA16S(aX, bX, 0); SE();
        LOAD_AS(aX, 1, 1, 0); LOAD_BS(bY, 1, 1);
        SB(); MFMA16S(aY, bX, 1); SE();
        LOAD_AS(aY, 1, 1, 1);
        SB(); MFMA16S(aX, bY, 0); SE();
        SB(); MFMA16S(aY, bY, 1); SE();
    }

    // ---- fused LSTM epilogue ----
    const int h = (n0 >> 2) + wn * 16 + (lane & 15);
    const float bi  = bx[h]            + bh[h];
    const float bff = bx[HIDN + h]     + bh[HIDN + h];
    const float bc  = bx[2 * HIDN + h] + bh[2 * HIDN + h];
    const float bo  = bx[3 * HIDN + h] + bh[3 * HIDN + h];

#pragma unroll
    for (int m = 0; m < 8; ++m) {
        const int rowb = m0 + wm * 128 + m * 16 + ((lane >> 4) << 2);
#pragma unroll
        for (int r = 0; r < 4; ++r) {
            const int row = rowb + r;
            const float gi = acc[m][0][r] + bi;
            const float gf = acc[m][1][r] + bff;
            const float gc = acc[m][2][r] + bc;
            const float go = acc[m][3][r] + bo;
            const float si = 1.f / (1.f + __expf(-gi));
            const float sf = 1.f / (1.f + __expf(-gf));
            const float tc = 1.f - 2.f / (__expf(2.f * gc) + 1.f);
            const float so = 1.f / (1.f + __expf(-go));
            const float c0v = c0[(int64_t)row * HIDN + h];
            const float c1 = sf * c0v + si * tc;
            const float th = 1.f - 2.f / (__expf(2.f * c1) + 1.f);
            out[(int64_t)row * HIDN + h] = so * th;                        // h1
            out[(int64_t)M_ROWS * HIDN + (int64_t)row * HIDN + h] = c1;    // c1
        }
    }
}

extern "C" void kernel_launch(void* const* d_in, const int* in_sizes, int n_in,
                              void* d_out, int out_size, void* d_ws, size_t ws_size,
                              hipStream_t stream) {
    const float* x  = (const float*)d_in[0];
    const float* h0 = (const float*)d_in[1];
    const float* c0 = (const float*)d_in[2];
    const float* Wx = (const float*)d_in[3];
    const float* bx = (const float*)d_in[4];
    const float* Wh = (const float*)d_in[5];
    const float* bh = (const float*)d_in[6];
    float* out = (float*)d_out;

    unsigned short* A = (unsigned short*)d_ws;                       // 33.5 MB
    unsigned short* B = A + (size_t)M_ROWS * K_DIM;                  // 16.8 MB

    pack_kernel<<<dim3(24576), dim3(256), 0, stream>>>(x, h0, Wx, Wh, A, B);
    lstm_gemm_kernel<<<dim3(512), dim3(512), 0, stream>>>(A, B, bx, bh, c0, out);
}